// Round 6
// baseline (275.703 us; speedup 1.0000x reference)
//
#include <hip/hip_runtime.h>
#include <hip/hip_bf16.h>
#include <math.h>

#define B 64
#define L 2048
#define C 1024          // D_K = D_Q
#define NH 8
#define DK 128
#define SCALE 0.08838834764831845f   // 1/sqrt(128)

// ---------------------------------------------------------------------------
// k_qs: qs[b, j] = bias[j] + sum_c q[b,c] * wq[j,c]   (64 x 1024)
__global__ void k_qs(const float* __restrict__ q, const float* __restrict__ wq,
                     const float* __restrict__ bq, float* __restrict__ qs) {
    int t = threadIdx.x, w = t >> 6, lane = t & 63;
    int j = blockIdx.x * 4 + w;
    float4 W[4];
#pragma unroll
    for (int kk = 0; kk < 4; kk++)
        W[kk] = *(const float4*)&wq[(size_t)j * C + kk * 256 + lane * 4];
    float bj = bq[j];
    for (int b = 0; b < B; b++) {
        float s = 0.f;
#pragma unroll
        for (int kk = 0; kk < 4; kk++) {
            float4 qv = *(const float4*)&q[(size_t)b * C + kk * 256 + lane * 4];
            s += W[kk].x * qv.x + W[kk].y * qv.y + W[kk].z * qv.z + W[kk].w * qv.w;
        }
#pragma unroll
        for (int off = 32; off; off >>= 1) s += __shfl_xor(s, off, 64);
        if (lane == 0) qs[(size_t)b * C + j] = s + bj;
    }
}

// ---------------------------------------------------------------------------
// k_qtilde: qtilde[b,n,c] = SCALE * sum_d qs[b, n*128+d] * wk[n*128+d, c]
__global__ void k_qtilde(const float* __restrict__ qs, const float* __restrict__ wk,
                         float* __restrict__ qtilde) {
    int n = blockIdx.x >> 2, cc = blockIdx.x & 3, bg = blockIdx.y;
    int t = threadIdx.x;
    int c = cc * 256 + t;
    __shared__ float qss[8][128];
    for (int p = 0; p < 4; p++) {
        int e = p * 256 + t;
        int i = e >> 7, d = e & 127;
        qss[i][d] = qs[(size_t)(bg * 8 + i) * C + n * DK + d];
    }
    __syncthreads();
    float acc[8];
#pragma unroll
    for (int i = 0; i < 8; i++) acc[i] = 0.f;
    for (int d = 0; d < DK; d++) {
        float wv = wk[(size_t)(n * DK + d) * C + c];
#pragma unroll
        for (int i = 0; i < 8; i++) acc[i] += qss[i][d] * wv;
    }
#pragma unroll
    for (int i = 0; i < 8; i++)
        qtilde[((size_t)(bg * 8 + i) * NH + n) * C + c] = acc[i] * SCALE;
}

// ---------------------------------------------------------------------------
// k_fused4: one streaming pass over k. 512 thr = 8 waves = 4 chunks x 2 hg.
// Wave: 4 heads (hg*4..+3) x 128 rows. Lane owns c-slots {kk*256+lane*4 .. +3}.
// Direct exp (softmax shift-invariance; f32 safe) -> partials add plainly.
// Prefetch distance 2 (4 rotating row buffers, statically indexed).
__global__ __launch_bounds__(512, 2) void k_fused4(
    const float* __restrict__ kmat, const float* __restrict__ qtilde,
    const unsigned char* __restrict__ mask,
    float* __restrict__ pout,             // (n*B + b)*L + l : exp(score)
    float* __restrict__ accpart,          // [b][lp][n][C]
    float* __restrict__ zpart) {          // [b][lp][n]
    const int b = blockIdx.x, lp = blockIdx.y;
    const int t = threadIdx.x, w = t >> 6, lane = t & 63;
    const int chunk = w >> 1;            // 0..3 (128 rows each)
    const int hg = w & 1;                // 0..1 (heads hg*4..hg*4+3)
    const int l0 = lp * 512 + chunk * 128;
    const int hl = lane & 3;

    __shared__ float ctxl[NH * C];       // 32 KB
    __shared__ float zl[NH];

    float4 qt[4][4];
#pragma unroll
    for (int j = 0; j < 4; j++)
#pragma unroll
        for (int kk = 0; kk < 4; kk++)
            qt[j][kk] = *(const float4*)&qtilde[((size_t)b * NH + hg * 4 + j) * C + kk * 256 + lane * 4];

    float4 acc[4][4];
#pragma unroll
    for (int j = 0; j < 4; j++)
#pragma unroll
        for (int kk = 0; kk < 4; kk++) acc[j][kk] = make_float4(0.f, 0.f, 0.f, 0.f);
    float zacc = 0.f;

    const float* kp = kmat + ((size_t)b * L + l0) * C + lane * 4;
    const unsigned char* mp = mask + (size_t)b * L + l0;

    // 4 rotating row buffers; at row r (slot r&3) we prefetch r+2 (slot (r+2)&3).
    float4 kv[4][4];
#pragma unroll
    for (int kk = 0; kk < 4; kk++) {
        kv[0][kk] = *(const float4*)(kp + kk * 256);
        kv[1][kk] = *(const float4*)(kp + (size_t)C + kk * 256);
    }

    for (int rb = 0; rb < 32; rb++) {
        uchar4 mb = *(const uchar4*)&mp[rb * 4];
        float ss[4];
#pragma unroll
        for (int rr = 0; rr < 4; rr++) {
            const int r = rb * 4 + rr;          // r & 3 == rr (rb*4 is 0 mod 4)
            // prefetch row r+2 into slot (rr+2)&3 (clamped; extra read harmless)
            {
                int lpre = r + 2; if (lpre > 127) lpre = 127;
                const float* np = kp + (size_t)lpre * C;
#pragma unroll
                for (int kk = 0; kk < 4; kk++)
                    kv[(rr + 2) & 3][kk] = *(const float4*)(np + kk * 256);
            }
            float s0 = 0.f, s1 = 0.f, s2 = 0.f, s3 = 0.f;
#pragma unroll
            for (int kk = 0; kk < 4; kk++) {
                float4 kq = kv[rr][kk];
                s0 += qt[0][kk].x * kq.x + qt[0][kk].y * kq.y + qt[0][kk].z * kq.z + qt[0][kk].w * kq.w;
                s1 += qt[1][kk].x * kq.x + qt[1][kk].y * kq.y + qt[1][kk].z * kq.z + qt[1][kk].w * kq.w;
                s2 += qt[2][kk].x * kq.x + qt[2][kk].y * kq.y + qt[2][kk].z * kq.z + qt[2][kk].w * kq.w;
                s3 += qt[3][kk].x * kq.x + qt[3][kk].y * kq.y + qt[3][kk].z * kq.z + qt[3][kk].w * kq.w;
            }
            // butterfly: lane ends with full score of head (lane&3)
            float a01 = (lane & 1) ? s1 : s0;
            float g01 = (lane & 1) ? s0 : s1;
            float a23 = (lane & 1) ? s3 : s2;
            float g23 = (lane & 1) ? s2 : s3;
            float u  = a01 + __shfl_xor(g01, 1, 64);   // head (lane&1)
            float v2 = a23 + __shfl_xor(g23, 1, 64);   // head 2+(lane&1)
            float keep = (lane & 2) ? v2 : u;
            float give = (lane & 2) ? u : v2;
            float v = keep + __shfl_xor(give, 2, 64);  // head (lane&3)
            v += __shfl_xor(v, 4, 64);
            v += __shfl_xor(v, 8, 64);
            v += __shfl_xor(v, 16, 64);
            v += __shfl_xor(v, 32, 64);
            unsigned char mk = (rr == 0) ? mb.x : (rr == 1) ? mb.y : (rr == 2) ? mb.z : mb.w;
            float p = __expf(mk ? -INFINITY : v);
            zacc += p;      // p is already the FULL row sum for head (lane&3):
            ss[rr] = p;     // zacc is the complete chunk-partial Z (no x-lane red.)
            // broadcast (permuted): pj = p of head (lane&3)^j
            float p1 = __shfl_xor(p, 1, 64);
            float p2 = __shfl_xor(p, 2, 64);
            float p3 = __shfl_xor(p1, 2, 64);
#pragma unroll
            for (int kk = 0; kk < 4; kk++) {
                float4 kq = kv[rr][kk];
                acc[0][kk].x += p  * kq.x; acc[0][kk].y += p  * kq.y; acc[0][kk].z += p  * kq.z; acc[0][kk].w += p  * kq.w;
                acc[1][kk].x += p1 * kq.x; acc[1][kk].y += p1 * kq.y; acc[1][kk].z += p1 * kq.z; acc[1][kk].w += p1 * kq.w;
                acc[2][kk].x += p2 * kq.x; acc[2][kk].y += p2 * kq.y; acc[2][kk].z += p2 * kq.z; acc[2][kk].w += p2 * kq.w;
                acc[3][kk].x += p3 * kq.x; acc[3][kk].y += p3 * kq.y; acc[3][kk].z += p3 * kq.z; acc[3][kk].w += p3 * kq.w;
            }
        }
        if (lane < 4) {
            float4 o = make_float4(ss[0], ss[1], ss[2], ss[3]);
            *(float4*)&pout[((size_t)(hg * 4 + lane) * B + b) * L + l0 + rb * 4] = o;
        }
    }

    // phased LDS merge across chunks; un-permute head mapping h = hg*4+(hl^j)
    __syncthreads();
    for (int ph = 0; ph < 4; ph++) {
        if (chunk == ph) {
#pragma unroll
            for (int j = 0; j < 4; j++) {
                int h = hg * 4 + (hl ^ j);
                float* dst = &ctxl[(size_t)h * C + lane * 4];
                if (ph == 0) {
#pragma unroll
                    for (int kk = 0; kk < 4; kk++)
                        *(float4*)&dst[kk * 256] = acc[j][kk];
                } else {
#pragma unroll
                    for (int kk = 0; kk < 4; kk++) {
                        float4 o = *(const float4*)&dst[kk * 256];
                        float4 a = acc[j][kk];
                        o.x += a.x; o.y += a.y; o.z += a.z; o.w += a.w;
                        *(float4*)&dst[kk * 256] = o;
                    }
                }
            }
            if (lane < 4) {
                if (ph == 0) zl[hg * 4 + lane] = zacc;
                else         zl[hg * 4 + lane] += zacc;
            }
        }
        __syncthreads();
    }
    float* ap = accpart + ((size_t)b * 4 + lp) * (NH * C);
#pragma unroll
    for (int i = 0; i < 4; i++) {
        int idx = t * 16 + i * 4;
        *(float4*)&ap[idx] = *(const float4*)&ctxl[idx];
    }
    if (t < NH) zpart[((size_t)b * 4 + lp) * NH + t] = zl[t];
}

// ---------------------------------------------------------------------------
// k_combine2: ctx[b,n,c] = (sum_lp accpart) / Z; ALSO scales pout by Zinv
// (fused former k_attnnorm). grid (64 b, 4 cq), 256 thr.
__global__ void k_combine2(const float* __restrict__ accpart, const float* __restrict__ zpart,
                           float* __restrict__ ctx, float* __restrict__ pout) {
    int b = blockIdx.x, cq = blockIdx.y;
    int t = threadIdx.x;
    int c = cq * 256 + t;
    __shared__ float zi[NH];
    if (t < NH) {
        float z = 0.f;
#pragma unroll
        for (int lpp = 0; lpp < 4; lpp++) z += zpart[((size_t)b * 4 + lpp) * NH + t];
        zi[t] = 1.0f / z;
    }
    __syncthreads();
#pragma unroll
    for (int n = 0; n < NH; n++) {
        float s = 0.f;
#pragma unroll
        for (int lpp = 0; lpp < 4; lpp++)
            s += accpart[(((size_t)b * 4 + lpp) * NH + n) * C + c];
        ctx[((size_t)b * NH + n) * C + c] = s * zi[n];
    }
    // attn normalize: rows (n, b), l-range [cq*512, cq*512+512)
#pragma unroll
    for (int n = 0; n < NH; n++) {
        float zin = zi[n];
        float2* pp = (float2*)&pout[((size_t)n * B + b) * L + cq * 512];
        float2 v = pp[t];
        v.x *= zin; v.y *= zin;
        pp[t] = v;
    }
}

// ---------------------------------------------------------------------------
// k_out: output[b, j] = bv[j] + sum_c wv[j,c] * ctx[b, n(j), c]
__global__ void k_out(const float* __restrict__ ctx, const float* __restrict__ wv,
                      const float* __restrict__ bv, float* __restrict__ out) {
    int t = threadIdx.x, w = t >> 6, lane = t & 63;
    int j = blockIdx.x * 4 + w;
    int n = j >> 7;
    float4 W[4];
#pragma unroll
    for (int kk = 0; kk < 4; kk++)
        W[kk] = *(const float4*)&wv[(size_t)j * C + kk * 256 + lane * 4];
    float bj = bv[j];
    for (int b = 0; b < B; b++) {
        float s = 0.f;
#pragma unroll
        for (int kk = 0; kk < 4; kk++) {
            float4 cv = *(const float4*)&ctx[((size_t)b * NH + n) * C + kk * 256 + lane * 4];
            s += W[kk].x * cv.x + W[kk].y * cv.y + W[kk].z * cv.z + W[kk].w * cv.w;
        }
#pragma unroll
        for (int off = 32; off; off >>= 1) s += __shfl_xor(s, off, 64);
        if (lane == 0) out[(size_t)b * (NH * DK) + j] = s + bj;
    }
}

// ---------------------------------------------------------------------------
extern "C" void kernel_launch(void* const* d_in, const int* in_sizes, int n_in,
                              void* d_out, int out_size, void* d_ws, size_t ws_size,
                              hipStream_t stream) {
    const float* q    = (const float*)d_in[0];
    const float* kmat = (const float*)d_in[1];
    const unsigned char* mask = (const unsigned char*)d_in[2];
    const float* wq = (const float*)d_in[3];
    const float* bq = (const float*)d_in[4];
    const float* wk = (const float*)d_in[5];
    // d_in[6] = w_ks_b: softmax-invariant -> unused.
    const float* wv = (const float*)d_in[7];
    const float* bv = (const float*)d_in[8];

    float* out  = (float*)d_out;            // (64, 1024)
    float* attn = out + B * NH * DK;        // (8*64, 2048): exp(s) -> scaled

    float* ws      = (float*)d_ws;
    float* qs      = ws;                     // 65536 floats (dead after k_qtilde)
    float* zpart   = ws;                     // 2048 floats overlay
    float* qtilde  = ws + 65536;             // 524288 floats, reused as ctx
    float* ctx     = qtilde;
    float* accpart = ws + 65536 + 524288;    // 2097152 floats

    hipLaunchKernelGGL(k_qs, dim3(256), dim3(256), 0, stream, q, wq, bq, qs);
    hipLaunchKernelGGL(k_qtilde, dim3(32, 8), dim3(256), 0, stream, qs, wk, qtilde);
    hipLaunchKernelGGL(k_fused4, dim3(64, 4), dim3(512), 0, stream,
                       kmat, qtilde, mask, attn, accpart, zpart);
    hipLaunchKernelGGL(k_combine2, dim3(64, 4), dim3(256), 0, stream,
                       accpart, zpart, ctx, attn);
    hipLaunchKernelGGL(k_out, dim3(256), dim3(256), 0, stream, ctx, wv, bv, out);
}

// Round 7
// 259.773 us; speedup vs baseline: 1.0613x; 1.0613x over previous
//
#include <hip/hip_runtime.h>
#include <hip/hip_bf16.h>
#include <math.h>

#define B 64
#define L 2048
#define C 1024          // D_K = D_Q
#define NH 8
#define DK 128
#define SCALE 0.08838834764831845f   // 1/sqrt(128)

// ---------------------------------------------------------------------------
// k_qs: qs[b, j] = bias[j] + sum_c q[b,c] * wq[j,c]   (64 x 1024)
__global__ void k_qs(const float* __restrict__ q, const float* __restrict__ wq,
                     const float* __restrict__ bq, float* __restrict__ qs) {
    int t = threadIdx.x, w = t >> 6, lane = t & 63;
    int j = blockIdx.x * 4 + w;
    float4 W[4];
#pragma unroll
    for (int kk = 0; kk < 4; kk++)
        W[kk] = *(const float4*)&wq[(size_t)j * C + kk * 256 + lane * 4];
    float bj = bq[j];
    for (int b = 0; b < B; b++) {
        float s = 0.f;
#pragma unroll
        for (int kk = 0; kk < 4; kk++) {
            float4 qv = *(const float4*)&q[(size_t)b * C + kk * 256 + lane * 4];
            s += W[kk].x * qv.x + W[kk].y * qv.y + W[kk].z * qv.z + W[kk].w * qv.w;
        }
#pragma unroll
        for (int off = 32; off; off >>= 1) s += __shfl_xor(s, off, 64);
        if (lane == 0) qs[(size_t)b * C + j] = s + bj;
    }
}

// ---------------------------------------------------------------------------
// k_qtilde: qtilde[b,n,c] = SCALE * sum_d qs[b, n*128+d] * wk[n*128+d, c]
__global__ void k_qtilde(const float* __restrict__ qs, const float* __restrict__ wk,
                         float* __restrict__ qtilde) {
    int n = blockIdx.x >> 2, cc = blockIdx.x & 3, bg = blockIdx.y;
    int t = threadIdx.x;
    int c = cc * 256 + t;
    __shared__ float qss[8][128];
    for (int p = 0; p < 4; p++) {
        int e = p * 256 + t;
        int i = e >> 7, d = e & 127;
        qss[i][d] = qs[(size_t)(bg * 8 + i) * C + n * DK + d];
    }
    __syncthreads();
    float acc[8];
#pragma unroll
    for (int i = 0; i < 8; i++) acc[i] = 0.f;
    for (int d = 0; d < DK; d++) {
        float wv = wk[(size_t)(n * DK + d) * C + c];
#pragma unroll
        for (int i = 0; i < 8; i++) acc[i] += qss[i][d] * wv;
    }
#pragma unroll
    for (int i = 0; i < 8; i++)
        qtilde[((size_t)(bg * 8 + i) * NH + n) * C + c] = acc[i] * SCALE;
}

// ---------------------------------------------------------------------------
// k_fused5: one streaming pass over k with LDS-staged pipeline.
// 512 thr = 8 waves; wave w: hg = w&1 (heads hg*4..+3), widx = w>>1.
// 64 groups of 8 rows. Per group: wave stages row w of group g+1
// (global->reg at group start, reg->LDS at group end = T14 async split),
// computes rows {2*widx, 2*widx+1} of group g from LDS for its 4 heads.
// Each k row hits HBM once per block; LDS lead time ~1300 cyc > HBM latency.
__global__ __launch_bounds__(512, 2) void k_fused5(
    const float* __restrict__ kmat, const float* __restrict__ qtilde,
    const unsigned char* __restrict__ mask,
    float* __restrict__ pout,             // (n*B + b)*L + l : exp(score)
    float* __restrict__ accpart,          // [b][lp][n][C]
    float* __restrict__ zpart) {          // [b][lp][n]
    const int b = blockIdx.x, lp = blockIdx.y;
    const int t = threadIdx.x, w = t >> 6, lane = t & 63;
    const int hg = w & 1;                // head group
    const int widx = w >> 1;             // row-pair index 0..3
    const int l_base = lp * 512;
    const int hl = lane & 3;

    __shared__ float kbuf[2 * 8 * 1024]; // 64 KB double-buffered k rows
    __shared__ float ctxl[NH * C];       // 32 KB
    __shared__ float zl[NH];

    float4 qt[4][4];
#pragma unroll
    for (int j = 0; j < 4; j++)
#pragma unroll
        for (int kk = 0; kk < 4; kk++)
            qt[j][kk] = *(const float4*)&qtilde[((size_t)b * NH + hg * 4 + j) * C + kk * 256 + lane * 4];

    float4 acc[4][4];
#pragma unroll
    for (int j = 0; j < 4; j++)
#pragma unroll
        for (int kk = 0; kk < 4; kk++) acc[j][kk] = make_float4(0.f, 0.f, 0.f, 0.f);
    float zacc = 0.f;

    const float* kgbase = kmat + ((size_t)b * L + l_base) * C + lane * 4;
    const unsigned char* mp = mask + (size_t)b * L + l_base;

    // prologue: stage group 0 (wave w loads+writes row w)
    {
        const float* gp = kgbase + (size_t)w * C;
        float4 s0 = *(const float4*)(gp);
        float4 s1 = *(const float4*)(gp + 256);
        float4 s2 = *(const float4*)(gp + 512);
        float4 s3 = *(const float4*)(gp + 768);
        float* dst = &kbuf[w * 1024 + lane * 4];
        *(float4*)(dst)       = s0;
        *(float4*)(dst + 256) = s1;
        *(float4*)(dst + 512) = s2;
        *(float4*)(dst + 768) = s3;
    }
    __syncthreads();

    for (int g = 0; g < 64; g++) {
        // issue next group's global loads early (latency hides under compute)
        float4 sreg[4];
        const bool has_next = (g < 63);
        if (has_next) {
            const float* gp = kgbase + (size_t)((g + 1) * 8 + w) * C;
#pragma unroll
            for (int kk = 0; kk < 4; kk++)
                sreg[kk] = *(const float4*)(gp + kk * 256);
        }

        // compute rows 2*widx, 2*widx+1 of group g from LDS
        const int l0 = g * 8 + 2 * widx;          // block-local row index
        const float* kb0 = &kbuf[(g & 1) * 8192 + (2 * widx) * 1024 + lane * 4];
        float4 kvr[2][4];
#pragma unroll
        for (int rr = 0; rr < 2; rr++)
#pragma unroll
            for (int kk = 0; kk < 4; kk++)
                kvr[rr][kk] = *(const float4*)&kb0[rr * 1024 + kk * 256];

#pragma unroll
        for (int rr = 0; rr < 2; rr++) {
            float s0 = 0.f, s1 = 0.f, s2 = 0.f, s3 = 0.f;
#pragma unroll
            for (int kk = 0; kk < 4; kk++) {
                float4 kq = kvr[rr][kk];
                s0 += qt[0][kk].x * kq.x + qt[0][kk].y * kq.y + qt[0][kk].z * kq.z + qt[0][kk].w * kq.w;
                s1 += qt[1][kk].x * kq.x + qt[1][kk].y * kq.y + qt[1][kk].z * kq.z + qt[1][kk].w * kq.w;
                s2 += qt[2][kk].x * kq.x + qt[2][kk].y * kq.y + qt[2][kk].z * kq.z + qt[2][kk].w * kq.w;
                s3 += qt[3][kk].x * kq.x + qt[3][kk].y * kq.y + qt[3][kk].z * kq.z + qt[3][kk].w * kq.w;
            }
            // butterfly: lane ends with full score of head hg*4 + (lane&3)
            float a01 = (lane & 1) ? s1 : s0;
            float g01 = (lane & 1) ? s0 : s1;
            float a23 = (lane & 1) ? s3 : s2;
            float g23 = (lane & 1) ? s2 : s3;
            float u  = a01 + __shfl_xor(g01, 1, 64);
            float v2 = a23 + __shfl_xor(g23, 1, 64);
            float keep = (lane & 2) ? v2 : u;
            float give = (lane & 2) ? u : v2;
            float v = keep + __shfl_xor(give, 2, 64);
            v += __shfl_xor(v, 4, 64);
            v += __shfl_xor(v, 8, 64);
            v += __shfl_xor(v, 16, 64);
            v += __shfl_xor(v, 32, 64);
            unsigned char mk = mp[l0 + rr];
            float p = __expf(mk ? -INFINITY : v);
            zacc += p;   // p is the FULL row sum for head (lane&3): no x-lane red.
            if (lane < 4)
                pout[((size_t)(hg * 4 + lane) * B + b) * L + l_base + l0 + rr] = p;
            // broadcast (permuted): pj = p of head (lane&3)^j
            float p1 = __shfl_xor(p, 1, 64);
            float p2 = __shfl_xor(p, 2, 64);
            float p3 = __shfl_xor(p1, 2, 64);
#pragma unroll
            for (int kk = 0; kk < 4; kk++) {
                float4 kq = kvr[rr][kk];
                acc[0][kk].x += p  * kq.x; acc[0][kk].y += p  * kq.y; acc[0][kk].z += p  * kq.z; acc[0][kk].w += p  * kq.w;
                acc[1][kk].x += p1 * kq.x; acc[1][kk].y += p1 * kq.y; acc[1][kk].z += p1 * kq.z; acc[1][kk].w += p1 * kq.w;
                acc[2][kk].x += p2 * kq.x; acc[2][kk].y += p2 * kq.y; acc[2][kk].z += p2 * kq.z; acc[2][kk].w += p2 * kq.w;
                acc[3][kk].x += p3 * kq.x; acc[3][kk].y += p3 * kq.y; acc[3][kk].z += p3 * kq.z; acc[3][kk].w += p3 * kq.w;
            }
        }

        // write staged row into the other half (vmcnt wait lands here; lead
        // time = whole compute phase, so the wait is effectively free)
        if (has_next) {
            float* dst = &kbuf[((g + 1) & 1) * 8192 + w * 1024 + lane * 4];
#pragma unroll
            for (int kk = 0; kk < 4; kk++)
                *(float4*)&dst[kk * 256] = sreg[kk];
        }
        __syncthreads();
    }

    // phased LDS merge across widx; un-permute head mapping h = hg*4+(hl^j)
    for (int ph = 0; ph < 4; ph++) {
        if (widx == ph) {
#pragma unroll
            for (int j = 0; j < 4; j++) {
                int h = hg * 4 + (hl ^ j);
                float* dst = &ctxl[(size_t)h * C + lane * 4];
                if (ph == 0) {
#pragma unroll
                    for (int kk = 0; kk < 4; kk++)
                        *(float4*)&dst[kk * 256] = acc[j][kk];
                } else {
#pragma unroll
                    for (int kk = 0; kk < 4; kk++) {
                        float4 o = *(const float4*)&dst[kk * 256];
                        float4 a = acc[j][kk];
                        o.x += a.x; o.y += a.y; o.z += a.z; o.w += a.w;
                        *(float4*)&dst[kk * 256] = o;
                    }
                }
            }
            if (lane < 4) {
                if (ph == 0) zl[hg * 4 + lane] = zacc;
                else         zl[hg * 4 + lane] += zacc;
            }
        }
        __syncthreads();
    }
    float* ap = accpart + ((size_t)b * 4 + lp) * (NH * C);
#pragma unroll
    for (int i = 0; i < 4; i++) {
        int idx = t * 16 + i * 4;
        *(float4*)&ap[idx] = *(const float4*)&ctxl[idx];
    }
    if (t < NH) zpart[((size_t)b * 4 + lp) * NH + t] = zl[t];
}

// ---------------------------------------------------------------------------
// k_combine2: ctx[b,n,c] = (sum_lp accpart) / Z; ALSO scales pout by Zinv
// (fused attn normalize). grid (64 b, 4 cq), 256 thr.
__global__ void k_combine2(const float* __restrict__ accpart, const float* __restrict__ zpart,
                           float* __restrict__ ctx, float* __restrict__ pout) {
    int b = blockIdx.x, cq = blockIdx.y;
    int t = threadIdx.x;
    int c = cq * 256 + t;
    __shared__ float zi[NH];
    if (t < NH) {
        float z = 0.f;
#pragma unroll
        for (int lpp = 0; lpp < 4; lpp++) z += zpart[((size_t)b * 4 + lpp) * NH + t];
        zi[t] = 1.0f / z;
    }
    __syncthreads();
#pragma unroll
    for (int n = 0; n < NH; n++) {
        float s = 0.f;
#pragma unroll
        for (int lpp = 0; lpp < 4; lpp++)
            s += accpart[(((size_t)b * 4 + lpp) * NH + n) * C + c];
        ctx[((size_t)b * NH + n) * C + c] = s * zi[n];
    }
    // attn normalize: rows (n, b), l-range [cq*512, cq*512+512)
#pragma unroll
    for (int n = 0; n < NH; n++) {
        float zin = zi[n];
        float2* pp = (float2*)&pout[((size_t)n * B + b) * L + cq * 512];
        float2 v = pp[t];
        v.x *= zin; v.y *= zin;
        pp[t] = v;
    }
}

// ---------------------------------------------------------------------------
// k_out: output[b, j] = bv[j] + sum_c wv[j,c] * ctx[b, n(j), c]
__global__ void k_out(const float* __restrict__ ctx, const float* __restrict__ wv,
                      const float* __restrict__ bv, float* __restrict__ out) {
    int t = threadIdx.x, w = t >> 6, lane = t & 63;
    int j = blockIdx.x * 4 + w;
    int n = j >> 7;
    float4 W[4];
#pragma unroll
    for (int kk = 0; kk < 4; kk++)
        W[kk] = *(const float4*)&wv[(size_t)j * C + kk * 256 + lane * 4];
    float bj = bv[j];
    for (int b = 0; b < B; b++) {
        float s = 0.f;
#pragma unroll
        for (int kk = 0; kk < 4; kk++) {
            float4 cv = *(const float4*)&ctx[((size_t)b * NH + n) * C + kk * 256 + lane * 4];
            s += W[kk].x * cv.x + W[kk].y * cv.y + W[kk].z * cv.z + W[kk].w * cv.w;
        }
#pragma unroll
        for (int off = 32; off; off >>= 1) s += __shfl_xor(s, off, 64);
        if (lane == 0) out[(size_t)b * (NH * DK) + j] = s + bj;
    }
}

// ---------------------------------------------------------------------------
extern "C" void kernel_launch(void* const* d_in, const int* in_sizes, int n_in,
                              void* d_out, int out_size, void* d_ws, size_t ws_size,
                              hipStream_t stream) {
    const float* q    = (const float*)d_in[0];
    const float* kmat = (const float*)d_in[1];
    const unsigned char* mask = (const unsigned char*)d_in[2];
    const float* wq = (const float*)d_in[3];
    const float* bq = (const float*)d_in[4];
    const float* wk = (const float*)d_in[5];
    // d_in[6] = w_ks_b: softmax-invariant -> unused.
    const float* wv = (const float*)d_in[7];
    const float* bv = (const float*)d_in[8];

    float* out  = (float*)d_out;            // (64, 1024)
    float* attn = out + B * NH * DK;        // (8*64, 2048): exp(s) -> scaled

    float* ws      = (float*)d_ws;
    float* qs      = ws;                     // 65536 floats (dead after k_qtilde)
    float* zpart   = ws;                     // 2048 floats overlay
    float* qtilde  = ws + 65536;             // 524288 floats, reused as ctx
    float* ctx     = qtilde;
    float* accpart = ws + 65536 + 524288;    // 2097152 floats

    hipLaunchKernelGGL(k_qs, dim3(256), dim3(256), 0, stream, q, wq, bq, qs);
    hipLaunchKernelGGL(k_qtilde, dim3(32, 8), dim3(256), 0, stream, qs, wk, qtilde);
    hipLaunchKernelGGL(k_fused5, dim3(64, 4), dim3(512), 0, stream,
                       kmat, qtilde, mask, attn, accpart, zpart);
    hipLaunchKernelGGL(k_combine2, dim3(64, 4), dim3(256), 0, stream,
                       accpart, zpart, ctx, attn);
    hipLaunchKernelGGL(k_out, dim3(256), dim3(256), 0, stream, ctx, wv, bv, out);
}